// Round 2
// 1097.497 us; speedup vs baseline: 1.1476x; 1.1476x over previous
//
#include <hip/hip_runtime.h>
#include <string.h>

// ---------------- problem constants ----------------
constexpr int M_LZ = 64;   // Lanczos steps. 32 FAILED (err 384>350): spectrum is Wigner-like,
                           // P^16 amplifies bottom edge ~2^16 -> need lambda_max to ~0.3%.

// CSR capacity per matrix (expected nnz * ~1.25)
constexpr int CAP_L0 = 26240, CAP_L1 = 118016, CAP_L2 = 52480, CAP_B1 = 39360, CAP_B2 = 78720;
constexpr int CB_L0 = 0;
constexpr int CB_L1D = CB_L0 + CAP_L0;
constexpr int CB_L1U = CB_L1D + CAP_L1;
constexpr int CB_L2  = CB_L1U + CAP_L1;
constexpr int CB_B1  = CB_L2 + CAP_L2;
constexpr int CB_B2  = CB_B1 + CAP_B1;
constexpr int CAP_TOT= CB_B2 + CAP_B2;   // 432832
constexpr int CB_B1T = CAP_TOT;
constexpr int CB_B2T = CB_B1T + CAP_B1;
constexpr int CAP_TOT2 = CB_B2T + CAP_B2; // 550912

// rowptr offsets (ints) within W_PTR region
constexpr int P_L0=0, P_L1D=1025, P_L1U=4098, P_L2=7171, P_B1=9220, P_B2=10245;
constexpr int P_B1T=13320, P_B2T=16393;   // region size 18444
// row-count offsets within W_CNT region
constexpr int C_L0=0, C_L1D=1024, C_L1U=4096, C_L2=7168, C_B1=9216, C_B2=10240;
constexpr int C_B1T=13312, C_B2T=16384;   // region size 18432

constexpr size_t HBUF  = (size_t)6144*128;          // 786432 words

// workspace layout (units: 4-byte words)
constexpr size_t W_CNT = 0;                         // 18432 ints
constexpr size_t W_PTR = 18432;                     // 18444 ints
constexpr size_t W_CUR = W_PTR + 18444;             // 5120 ints
constexpr size_t W_CIDX= W_CUR + 5120;              // CAP_TOT2 ints
constexpr size_t W_VAL = W_CIDX + CAP_TOT2;         // CAP_TOT2 floats
// Lanczos: v_0 start vector + write-once step-indexed packets PK[j][row]=(w_j,v_j,v_{j-1},pad)
constexpr size_t W_V0  = W_VAL + CAP_TOT2;          // 6144
constexpr size_t W_PK  = W_V0 + 6144;               // 64*6144*4 = 1572864
// tridiagonal entries: TT[g][j] = (a, g, n), padded to one 128B line each
constexpr size_t W_TT  = W_PK + (size_t)64*6144*4;  // 3*64*32 = 6144
constexpr size_t W_EPS = W_TT + 6144;               // 4*32 (per-group padded line)
constexpr size_t W_UV  = W_EPS + 128;               // 4*3072 (U_d,V_d,U_u,V_u)
// write-once harmonic buffers: [s][row][128]
constexpr size_t W_H   = W_UV + 4*3072;             // 15*HBUF
constexpr size_t W_SCAT= W_H + 15*HBUF;
constexpr size_t S0_OFF= 0;                          // 1024 x 384
constexpr size_t S1_OFF= (size_t)1024*384;           // 3072 x 640
constexpr size_t S2_OFF= S1_OFF + (size_t)3072*640;  // 2048 x 384
constexpr size_t SCAT_TOT = S2_OFF + (size_t)2048*384;
constexpr size_t W_WCAT= W_SCAT + SCAT_TOT;          // 1408*128 concatenated weights
constexpr size_t WC0=0, WC1=(size_t)384*128, WC2=WC1+(size_t)640*128;
// per-block Lanczos slot lines, step-indexed (write-once per launch): [j][b] -> 8 words (32B)
// word layout: [0]=seq(int) [2..3]=(A,G) [4]=N   (seq zeroed each launch by k_wprep)
constexpr size_t W_SLOT= W_WCAT + (size_t)1408*128;  // 64*2048*8 = 1048576
// per-block arrival flags (monotonic phase counters), padded 128B each
constexpr size_t W_FLG = W_SLOT + 1048576;           // 2048*32 = 65536
// release copies: 4 groups x 16 leaves, padded 128B each.
// Leaf line layout (words): [0]=seq(int) [2..3]=(a,g) [4]=ib  (payload used by Lanczos barriers)
constexpr size_t W_REL = W_FLG + 65536;              // 2048

__device__ __forceinline__ float wredf(float v){
  #pragma unroll
  for(int o=32;o;o>>=1) v += __shfl_xor(v,o,64);
  return v;
}
__device__ __forceinline__ int wredi(int v){
  #pragma unroll
  for(int o=32;o;o>>=1) v += __shfl_xor(v,o,64);
  return v;
}
// fold 4 nnz-subgroups (lanes l, l^16, l^32, l^48) for 8 accumulator comps
__device__ __forceinline__ void red4x2(float4& a0, float4& a1){
  #pragma unroll
  for (int o=16;o<=32;o<<=1){
    a0.x+=__shfl_xor(a0.x,o,64); a0.y+=__shfl_xor(a0.y,o,64);
    a0.z+=__shfl_xor(a0.z,o,64); a0.w+=__shfl_xor(a0.w,o,64);
    a1.x+=__shfl_xor(a1.x,o,64); a1.y+=__shfl_xor(a1.y,o,64);
    a1.z+=__shfl_xor(a1.z,o,64); a1.w+=__shfl_xor(a1.w,o,64);
  }
}

// agent-scope (coherence-point) ops
__device__ __forceinline__ float ldc(const float* p){
  return __hip_atomic_load(p, __ATOMIC_RELAXED, __HIP_MEMORY_SCOPE_AGENT);
}
__device__ __forceinline__ float2 ldc2(const float* p){
  unsigned long long u = __hip_atomic_load((const unsigned long long*)p,
                          __ATOMIC_RELAXED, __HIP_MEMORY_SCOPE_AGENT);
  float2 r; memcpy(&r,&u,8); return r;
}
__device__ __forceinline__ void stc(float* p, float v){
  __hip_atomic_store(p, v, __ATOMIC_RELAXED, __HIP_MEMORY_SCOPE_AGENT);
}
__device__ __forceinline__ void stc2(float* p, float2 v){
  unsigned long long u; memcpy(&u,&v,8);
  __hip_atomic_store((unsigned long long*)p, u, __ATOMIC_RELAXED, __HIP_MEMORY_SCOPE_AGENT);
}
__device__ __forceinline__ int ldci(const int* p){
  return __hip_atomic_load(p, __ATOMIC_RELAXED, __HIP_MEMORY_SCOPE_AGENT);
}
__device__ __forceinline__ void stci(int* p, int v){
  __hip_atomic_store(p, v, __ATOMIC_RELAXED, __HIP_MEMORY_SCOPE_AGENT);
}

// ---- plain flag-array barrier (A / eig / harmonic / pre-E). No payload. ----
__device__ __forceinline__ void barx(float* ws, int b, int grp, int lbase, int Ng,
                                     bool chk, int lb, int ph){
  const int t = threadIdx.x;
  int* flg = (int*)ws + W_FLG;
  int* rel = (int*)ws + W_REL;
  __builtin_amdgcn_s_waitcnt(0);   // every thread drains its stores
  __syncthreads();
  if (t==0) stci(flg + (size_t)b*32, ph+1);
  if (chk){
    for (int s=t; s<Ng; s+=256){
      const int* f = flg + (size_t)(lbase+s)*32;
      while (ldci(f) < ph+1) __builtin_amdgcn_s_sleep(1);
    }
    __syncthreads();                // all threads saw all flags before release
    if (t==0){
      #pragma unroll
      for (int i=0;i<16;i++) stci(rel + (size_t)(grp*16+i)*32, ph+1);
    }
    __syncthreads();
  } else {
    if (t==0){
      const int* r = rel + (size_t)(grp*16 + (lb&15))*32;
      while (ldci(r) < ph+1) __builtin_amdgcn_s_sleep(1);
    }
    __syncthreads();
  }
}

// ---- Lanczos barrier: seq-embedded slot lines + (a,g,ib) payload in release leaves ----
// Block side: one 32B line carries both partials and arrival seq (payload stores,
// vmcnt drain, then seq store -> checker polls ONE line per block per step).
// Pollers read next-step coefficients from the leaf line they already poll.
// Payload overwrite for step j+1 happens only after every participant posted its
// step-j+1 slot, which is strictly after it consumed payload j -> no reuse race.
__device__ __forceinline__ void bar_lz(float* ws, int b, int grp, int lbase, int Lg,
                                       bool chk, int lb, int ph, int j,
                                       float* shr, float* redm,
                                       float& a_o, float& g_o, float& ib_o){
  const int t = threadIdx.x, lane = t&63, wvv = t>>6;
  __builtin_amdgcn_s_waitcnt(0);   // drain PK / own stores
  __syncthreads();
  if (t==0){
    float A0=redm[0]+redm[1]+redm[2]+redm[3];
    float G0=redm[4]+redm[5]+redm[6]+redm[7];
    float N0=redm[8]+redm[9]+redm[10]+redm[11];
    float* sl = ws + W_SLOT + ((size_t)j*2048 + b)*8;
    stc2(sl+2, make_float2(A0,G0)); stc(sl+4, N0);
    __builtin_amdgcn_s_waitcnt(0);           // payload before seq
    stci((int*)sl, ph+1);
  }
  if (chk){
    float pa=0.f, pg=0.f, pn=0.f;
    for (int s=t; s<Lg; s+=256){
      const float* sl = ws + W_SLOT + ((size_t)j*2048 + lbase+s)*8;
      while (ldci((const int*)sl) < ph+1) __builtin_amdgcn_s_sleep(1);
      float2 ag = ldc2(sl+2); float nn = ldc(sl+4);
      pa+=ag.x; pg+=ag.y; pn+=nn;
    }
    pa=wredf(pa); pg=wredf(pg); pn=wredf(pn);
    if (lane==0){ shr[0*4+wvv]=pa; shr[1*4+wvv]=pg; shr[2*4+wvv]=pn; }
    __syncthreads();
    if (t==0){
      float a=shr[0]+shr[1]+shr[2]+shr[3];
      float g=shr[4]+shr[5]+shr[6]+shr[7];
      float n=shr[8]+shr[9]+shr[10]+shr[11];
      float ib = 1.f/sqrtf(fmaxf(n - a*a - g*g, 1e-20f));
      float* TT = ws + W_TT + (size_t)(grp*64 + j)*32;   // for eig later (write-once)
      stc2(TT, make_float2(a,g)); stc(TT+2, n);
      #pragma unroll
      for (int i=0;i<16;i++){
        float* lf = ws + W_REL + (size_t)(grp*16+i)*32;
        stc2(lf+2, make_float2(a,g)); stc(lf+4, ib);
      }
      __builtin_amdgcn_s_waitcnt(0);   // payload globally visible before seq
      #pragma unroll
      for (int i=0;i<16;i++)
        stci((int*)(ws + W_REL) + (size_t)(grp*16+i)*32, ph+1);
      shr[0]=a; shr[1]=g; shr[2]=ib;
    }
    __syncthreads();
  } else {
    if (t==0){
      const float* lf = ws + W_REL + (size_t)(grp*16 + (lb&15))*32;
      while (ldci((const int*)lf) < ph+1) __builtin_amdgcn_s_sleep(1);
      float2 ag = ldc2(lf+2); float ib = ldc(lf+4);
      shr[0]=ag.x; shr[1]=ag.y; shr[2]=ib;
    }
    __syncthreads();
  }
  a_o = shr[0]; g_o = shr[1]; ib_o = shr[2];
}

// ---------------- weight prep + zeroing of counters/flags/slot-seqs ----------------
__global__ void k_wprep(const float* Wd,const float* Wu,const float* Wh,
                        const float* Wb1,const float* Wb2, float* ws){
  int t = blockIdx.x*256 + threadIdx.x;
  if (t >= 16384) return;
  int* wsi = (int*)ws;
  if (t < 5120) wsi[W_CNT + 13312 + t] = 0;          // transpose col counters
  if (t < 5120) wsi[W_CUR + t] = 0;                  // cursors
  for (int i=t; i<65536+2048; i+=16384) wsi[W_FLG+i] = 0;  // flags + releases
  for (int i=t; i<131072; i+=16384) wsi[W_SLOT + (size_t)i*8] = 0;  // slot seq words
  float sd = Wd[t]  + Wd[16384+t]  + Wd[32768+t];
  float su = Wu[t]  + Wu[16384+t]  + Wu[32768+t];
  float s1 = Wb1[t] + Wb1[16384+t] + Wb1[32768+t];
  float s2 = Wb2[t] + Wb2[16384+t] + Wb2[32768+t];
  float wh = Wh[t];
  float* W0 = ws + W_WCAT + WC0;
  float* W1 = ws + W_WCAT + WC1;
  float* W2 = ws + W_WCAT + WC2;
  W0[t]=sd; W0[16384+t]=s1; W0[32768+t]=wh;
  W1[t]=sd; W1[16384+t]=su; W1[32768+t]=s1; W1[49152+t]=s2; W1[65536+t]=wh;
  W2[t]=su; W2[16384+t]=s2; W2[32768+t]=wh;
}

// ---------------- CSR extraction (proven) ----------------
__device__ __forceinline__ void mat_meta(int wid, const float* L0,const float* L1d,const float* L1u,
    const float* L2,const float* B1,const float* B2,
    const float*& M,int& ncol,int& lrow,int& co,int& po,int& cb,int& cap,int& tco){
  if (wid < 1024){ M=L0;  ncol=1024; lrow=wid;        co=C_L0;  po=P_L0;  cb=CB_L0;  cap=CAP_L0; tco=-1; }
  else if (wid < 4096){ M=L1d; ncol=3072; lrow=wid-1024;  co=C_L1D; po=P_L1D; cb=CB_L1D; cap=CAP_L1; tco=-1; }
  else if (wid < 7168){ M=L1u; ncol=3072; lrow=wid-4096;  co=C_L1U; po=P_L1U; cb=CB_L1U; cap=CAP_L1; tco=-1; }
  else if (wid < 9216){ M=L2;  ncol=2048; lrow=wid-7168;  co=C_L2;  po=P_L2;  cb=CB_L2;  cap=CAP_L2; tco=-1; }
  else if (wid < 10240){ M=B1; ncol=3072; lrow=wid-9216;  co=C_B1;  po=P_B1;  cb=CB_B1;  cap=CAP_B1; tco=C_B1T; }
  else { M=B2; ncol=2048; lrow=wid-10240; co=C_B2;  po=P_B2;  cb=CB_B2;  cap=CAP_B2; tco=C_B2T; }
}

__global__ void k_count(const float* L0,const float* L1d,const float* L1u,const float* L2,
                        const float* B1,const float* B2,int* cnt){
  int wid = blockIdx.x*4 + (threadIdx.x>>6);
  int lane = threadIdx.x & 63;
  if (wid >= 13312) return;
  const float* M; int ncol,lrow,co,po,cb,cap,tco;
  mat_meta(wid,L0,L1d,L1u,L2,B1,B2,M,ncol,lrow,co,po,cb,cap,tco);
  const float4* row4 = (const float4*)(M + (size_t)lrow*ncol);
  int c = 0;
  for (int j0=0; j0<ncol; j0+=256){
    float4 v = row4[(j0>>2)+lane];
    int n0=v.x!=0.f, n1=v.y!=0.f, n2=v.z!=0.f, n3=v.w!=0.f;
    c += n0+n1+n2+n3;
    if (tco>=0){
      int jb = j0 + lane*4;
      if (n0) atomicAdd(cnt+tco+jb,   1);
      if (n1) atomicAdd(cnt+tco+jb+1, 1);
      if (n2) atomicAdd(cnt+tco+jb+2, 1);
      if (n3) atomicAdd(cnt+tco+jb+3, 1);
    }
  }
  c = wredi(c);
  if (lane==0) cnt[co+lrow] = c;
}

__global__ void k_prefix(const int* cnt, int* ptr, int* cur){
  __shared__ int lds[257];
  const int rows[8]={1024,3072,3072,2048,1024,3072,3072,2048};
  const int cofs[8]={C_L0,C_L1D,C_L1U,C_L2,C_B1,C_B2,C_B1T,C_B2T};
  const int pofs[8]={P_L0,P_L1D,P_L1U,P_L2,P_B1,P_B2,P_B1T,P_B2T};
  int b=blockIdx.x, t=threadIdx.x;
  int R=rows[b]; const int* c=cnt+cofs[b]; int* p=ptr+pofs[b];
  int* cc = (b==6)? cur : (b==7)? cur+3072 : nullptr;
  int chunk=(R+255)/256;
  int lo=t*chunk, hi=min(R,lo+chunk);
  int s=0;
  for(int i=lo;i<hi;i++) s+=c[i];
  lds[t]=s; __syncthreads();
  if(t==0){ int run=0; for(int i=0;i<256;i++){int x=lds[i];lds[i]=run;run+=x;} lds[256]=run; }
  __syncthreads();
  int run=lds[t];
  for(int i=lo;i<hi;i++){ p[i]=run; if(cc) cc[i]=run; run+=c[i]; }
  if(t==0) p[R]=lds[256];
}

__global__ void k_fill(const float* L0,const float* L1d,const float* L1u,const float* L2,
                       const float* B1,const float* B2,const int* ptr,int* cidx,float* val){
  int wid = blockIdx.x*4 + (threadIdx.x>>6);
  int lane = threadIdx.x & 63;
  if (wid >= 13312) return;
  const float* M; int ncol,lrow,co,po,cb,cap,tco;
  mat_meta(wid,L0,L1d,L1u,L2,B1,B2,M,ncol,lrow,co,po,cb,cap,tco);
  const float4* row4 = (const float4*)(M + (size_t)lrow*ncol);
  int base = ptr[po+lrow];
  int run = 0;
  for (int j0=0; j0<ncol; j0+=256){
    float4 v = row4[(j0>>2)+lane];
    int n0=v.x!=0.f, n1=v.y!=0.f, n2=v.z!=0.f, n3=v.w!=0.f;
    int local = n0+n1+n2+n3;
    int incl = local;
    #pragma unroll
    for (int o=1;o<64;o<<=1){
      int tmp = __shfl_up(incl,o,64);
      if (lane>=o) incl += tmp;
    }
    int tot = __shfl(incl,63,64);
    int pos = base + run + incl - local;
    int jb = j0 + lane*4;
    if (n0){ if(pos<cap){cidx[cb+pos]=jb;   val[cb+pos]=v.x;} pos++; }
    if (n1){ if(pos<cap){cidx[cb+pos]=jb+1; val[cb+pos]=v.y;} pos++; }
    if (n2){ if(pos<cap){cidx[cb+pos]=jb+2; val[cb+pos]=v.z;} pos++; }
    if (n3){ if(pos<cap){cidx[cb+pos]=jb+3; val[cb+pos]=v.w;} pos++; }
    run += tot;
  }
}

__global__ void k_fillT(float* ws){
  int wid = blockIdx.x*4 + (threadIdx.x>>6);
  int lane = threadIdx.x & 63;
  if (wid >= 4096) return;
  int* wsi=(int*)ws;
  const int* ptr=wsi+W_PTR; int* cidx=wsi+W_CIDX; float* val=ws+W_VAL;
  int* cur=wsi+W_CUR;
  if (wid < 1024){
    int r=wid;
    int e=ptr[P_B1+r+1];
    for(int k=ptr[P_B1+r]+lane;k<e;k+=64){
      int c=cidx[CB_B1+k]; float v=val[CB_B1+k];
      int pos=atomicAdd(cur+c,1);
      cidx[CB_B1T+pos]=r; val[CB_B1T+pos]=v;
    }
  } else {
    int r=wid-1024;
    int e=ptr[P_B2+r+1];
    for(int k=ptr[P_B2+r]+lane;k<e;k+=64){
      int c=cidx[CB_B2+k]; float v=val[CB_B2+k];
      int pos=atomicAdd(cur+3072+c,1);
      cidx[CB_B2T+pos]=r; val[CB_B2T+pos]=v;
    }
  }
}

// ================= FUSED PERSISTENT SOLVER =================
// 2048 blocks x 256 threads, 8 blocks/CU.
// Groups by ROWS: g0 [0,336) /1024 rows; g1 [336,1360) /3072; g2 [1360,2048) /2048.
// Lanczos runs on exactly crows/4 blocks per group (one wave per row):
// g0:256, g1:768, g2:512 (=1536). The surplus 512 blocks run Phase C (forward
// SpMMs) OVERLAPPED with the latency-bound Lanczos chain, then jump their phase
// counter to the eig barrier (flags are monotonic, so skipping values is safe).
// Phase schedule (ph): A=0, lz=1..64 (slot-seq based), eig=65, harm=66..80, pre-E=81.
__global__ __launch_bounds__(256,8) void k_solve(float* ws,
    const float* z0,const float* z1,const float* z2,
    const float* adw,const float* adb,const float* auw,const float* aub,
    float* out){
  const int b = blockIdx.x, t = threadIdx.x;
  const int wv = t>>6, lane = t&63;
  const int sg = lane>>4, chn = lane&15;   // nnz-subgroup, channel-sixteenth
  const int* wsi=(const int*)ws;
  const int* ptr=wsi+W_PTR; const int* cidx=wsi+W_CIDX; const float* val=ws+W_VAL;

  __shared__ float smem[2616];             // 10464 B
  float* Sl  = smem;                       // [544]   phase E
  float* Wl  = smem + 544;                 // [2048]  phase E
  float* TTa = smem;                       // [64]    eig (alias, disjoint in time)
  float* TTb = smem + 64;                  // [64]
  float* redm= smem + 2592;                // [12]    phase B block partials
  float* shr = smem + 2604;                // [12]    barrier payload scratch

  // group mapping
  int g, nb, crows, bbase, Ng, lb, Lg;
  if (b<336){ g=0; lb=b;        nb=0;    crows=1024; bbase=0;    Ng=336;  Lg=256; }
  else if (b<1360){ g=1; lb=b-336;  nb=1024; crows=3072; bbase=336;  Ng=1024; Lg=768; }
  else { g=2; lb=b-1360; nb=4096; crows=2048; bbase=1360; Ng=688;  Lg=512; }
  const int gwv = lb*4 + wv;               // wave id within group (harmonic)
  const int GW  = Ng*4;                    // waves per group
  const bool chk = (b==bbase);
  const float* zc = (g==0)?z0:(g==1)?z1:z2;
  int ph = 0;

  // ---- Phase A: v_0 init + attention U,V ----
  { int i = b*256+t;
    if (i < 6144){
      float invs = (i<1024)?0.03125f:(i<4096)?0.0180421959f:0.0220970869f;
      unsigned uu=(unsigned)i*2654435761u; uu^=uu>>16; uu*=2246822519u; uu^=uu>>13;
      stc(ws+W_V0+i, (uu&1)?invs:-invs);     // v_0
    }
  }
  { int gw = b*4+wv;
    if (gw < 3072){
      float2 x  = ((const float2*)(z1+(size_t)gw*128))[lane];
      float2 a0 = ((const float2*)adw)[lane];
      float2 a1 = ((const float2*)adw)[64+lane];
      float2 b0 = ((const float2*)auw)[lane];
      float2 b1 = ((const float2*)auw)[64+lane];
      float ud=x.x*a0.x+x.y*a0.y, vd=x.x*a1.x+x.y*a1.y;
      float uu=x.x*b0.x+x.y*b0.y, vu=x.x*b1.x+x.y*b1.y;
      ud=wredf(ud); vd=wredf(vd); uu=wredf(uu); vu=wredf(vu);
      if(lane==0){ stc(ws+W_UV+gw,ud); stc(ws+W_UV+3072+gw,vd);
                   stc(ws+W_UV+6144+gw,uu); stc(ws+W_UV+9216+gw,vu); }
    }
  }
  barx(ws, b, 3, 0, 2048, b==0, b, ph); ph++;   // global: v_0, UV visible

  if (lb < Lg){
    // ---- Phase B: M_LZ Lanczos steps, one wave per row exactly ----
    // PK packet: PK[j][q] = (w_j[q], v_j[q], v_{j-1}[q]) written by row q's wave
    // during step j -> step j+1's gather is ONE dwordx4 instead of 3 scattered b32.
    const int p = lb*4 + wv;
    const int gp = nb + p;
    float a=0.f, gmm=0.f, ib=1.f;
    float vp_m1=0.f, vp_m2=0.f, wp_m1=0.f;   // own-row history (lane0-maintained)
    for (int j=0;j<M_LZ;j++){
      float wp=0.f;
      if (j==0){
        const float* v0 = ws + W_V0;
        #define GZ(PP,CBB) { const int* rp=ptr+PP; int e=rp[p+1]; \
          for (int k=rp[p]+lane;k<e;k+=64){ wp += val[CBB+k]*v0[nb+cidx[CBB+k]]; } }
        if (g==0){ GZ(P_L0,CB_L0) }
        else if (g==1){ GZ(P_L1D,CB_L1D) GZ(P_L1U,CB_L1U) }
        else { GZ(P_L2,CB_L2) }
        #undef GZ
      } else {
        const float4* pk = (const float4*)(ws + W_PK) + (size_t)(j-1)*6144 + nb;
        #define GP(PP,CBB) { const int* rp=ptr+PP; int e=rp[p+1]; \
          for (int k=rp[p]+lane;k<e;k+=64){ float v=val[CBB+k]; float4 pq=pk[cidx[CBB+k]]; \
            wp += v*((pq.x - a*pq.y - gmm*pq.z)*ib); } }
        if (g==0){ GP(P_L0,CB_L0) }
        else if (g==1){ GP(P_L1D,CB_L1D) GP(P_L1U,CB_L1U) }
        else { GP(P_L2,CB_L2) }
        #undef GP
      }
      wp = wredf(wp);
      if (lane==0){
        float vp;
        if (j==0) vp = ws[W_V0+gp];
        else      vp = (wp_m1 - a*vp_m1 - gmm*vp_m2)*ib;
        float* pkw = ws + W_PK + ((size_t)j*6144 + gp)*4;
        stc2(pkw, make_float2(wp, vp)); stc(pkw+2, vp_m1);
        redm[0*4+wv]=vp*wp; redm[1*4+wv]=vp_m1*wp; redm[2*4+wv]=wp*wp;
        vp_m2 = vp_m1; vp_m1 = vp; wp_m1 = wp;
      }
      bar_lz(ws, b, g, bbase, Lg, chk, lb, 1+j, j, shr, redm, a, gmm, ib);
    }
    ph = 1 + M_LZ;
  } else {
    // ---- Phase C overlapped with Lanczos: forward SpMMs on 512 surplus blocks ----
    int cbi = (g==0)? (lb-256) : (g==1)? (80 + lb-768) : (336 + lb-512);  // [0,512)
    for (int wid2 = cbi*4+wv; wid2 < 18432; wid2 += 2048){
      int task,p2;
      if(wid2<1024){task=0;p2=wid2;}
      else if(wid2<2048){task=1;p2=wid2-1024;}
      else if(wid2<5120){task=2;p2=wid2-2048;}
      else if(wid2<8192){task=3;p2=wid2-5120;}
      else if(wid2<11264){task=4;p2=wid2-8192;}
      else if(wid2<13312){task=5;p2=wid2-11264;}
      else if(wid2<16384){task=6;p2=wid2-13312;}
      else {task=7;p2=wid2-16384;}
      const float* in; const int* rp; int cb2; float* outp; int ostride;
      int mode=0; float Vp=0.f, bb=0.f; const float* U=nullptr;
      switch(task){
        case 0: rp=ptr+P_L0;  cb2=CB_L0;  in=z0; outp=ws+W_SCAT+S0_OFF+0;   ostride=384; break;
        case 1: rp=ptr+P_B1;  cb2=CB_B1;  in=z1; outp=ws+W_SCAT+S0_OFF+128; ostride=384; break;
        case 2: rp=ptr+P_L1D; cb2=CB_L1D; in=z1; outp=ws+W_SCAT+S1_OFF+0;   ostride=640;
                mode=1; U=ws+W_UV; Vp=ws[W_UV+3072+p2]; bb=adb[0]; break;
        case 3: rp=ptr+P_L1U; cb2=CB_L1U; in=z1; outp=ws+W_SCAT+S1_OFF+128; ostride=640;
                mode=1; U=ws+W_UV+6144; Vp=ws[W_UV+9216+p2]; bb=aub[0]; break;
        case 4: rp=ptr+P_B2;  cb2=CB_B2;  in=z2; outp=ws+W_SCAT+S1_OFF+384; ostride=640; break;
        case 5: rp=ptr+P_L2;  cb2=CB_L2;  in=z2; outp=ws+W_SCAT+S2_OFF+0;   ostride=384; break;
        case 6: rp=ptr+P_B1T; cb2=CB_B1T; in=z0; outp=ws+W_SCAT+S1_OFF+256; ostride=640; break;
        default:rp=ptr+P_B2T; cb2=CB_B2T; in=z1; outp=ws+W_SCAT+S2_OFF+128; ostride=384; break;
      }
      float4 a0={0.f,0.f,0.f,0.f}, a1={0.f,0.f,0.f,0.f};
      int e=rp[p2+1];
      for (int k=rp[p2]+sg; k<e; k+=4){
        int q = cidx[cb2+k];
        float v;
        if (mode) v = 1.0f/(1.0f+__expf(-(U[q]+Vp+bb)));
        else v = val[cb2+k];
        const float* sr = in + (size_t)q*128;
        float4 x0 = ((const float4*)sr)[chn*2];
        float4 x1 = ((const float4*)sr)[chn*2+1];
        a0.x+=v*x0.x; a0.y+=v*x0.y; a0.z+=v*x0.z; a0.w+=v*x0.w;
        a1.x+=v*x1.x; a1.y+=v*x1.y; a1.z+=v*x1.z; a1.w+=v*x1.w;
      }
      red4x2(a0, a1);
      if (sg==0){
        float* dst = outp + (size_t)p2*ostride;
        stc2(dst+chn*8,   make_float2(a0.x,a0.y));
        stc2(dst+chn*8+2, make_float2(a0.z,a0.w));
        stc2(dst+chn*8+4, make_float2(a1.x,a1.y));
        stc2(dst+chn*8+6, make_float2(a1.z,a1.w));
      }
    }
    ph = 1 + M_LZ;   // jump to eig-barrier phase (flags monotonic -> safe)
  }

  // ---- eig: one wave of each group's checker block ----
  if (chk && t<64){
    int i = t;
    double lo=1e300, hi=-1e300;
    if (i<M_LZ){
      const float* TT = ws + W_TT + (size_t)(g*64 + i)*32;
      float aa=TT[0], gg=TT[1], nn=TT[2];
      TTa[i]=aa; TTb[i]=sqrtf(fmaxf(nn-aa*aa-gg*gg,1e-20f));
    }
    if (i<M_LZ){
      double r=(i? fabs((double)TTb[i-1]):0.0) + (i<M_LZ-1? fabs((double)TTb[i]):0.0);
      lo=(double)TTa[i]-r; hi=(double)TTa[i]+r;
    }
    #pragma unroll
    for(int o=32;o;o>>=1){ lo=fmin(lo,__shfl_xor(lo,o,64)); hi=fmax(hi,__shfl_xor(hi,o,64)); }
    lo -= 1.0; hi += 1.0;
    for (int round=0; round<4; round++){
      double x = lo + (hi-lo)*(double)(i+1)/65.0;
      double d = 1.0; int cnt2=0;
      for (int k2=0;k2<M_LZ;k2++){
        double bi = k2? (double)TTb[k2-1] : 0.0;
        d = ((double)TTa[k2]-x) - bi*bi/d;
        if (d==0.0) d = -1e-300;
        if (d<0.0) cnt2++;
      }
      double nlo = (cnt2< M_LZ)? x : -1e300;
      double nhi = (cnt2==M_LZ)? x :  1e300;
      #pragma unroll
      for(int o=32;o;o>>=1){ nlo=fmax(nlo,__shfl_xor(nlo,o,64)); nhi=fmin(nhi,__shfl_xor(nhi,o,64)); }
      if (nlo>-1e299) lo=nlo;
      if (nhi< 1e299) hi=nhi;
    }
    double lam = 0.5*(lo+hi);
    if (i==0) stc(ws+W_EPS+(size_t)g*32, (lam>0.0)? (float)(1.0/lam) : 0.1f);
  }
  barx(ws, b, g, bbase, Ng, chk, lb, ph); ph++;   // eps visible; C-blocks rejoin here

  // ---- Phase D: 16 harmonic steps (one wave per row, 4-way nnz-parallel) ----
  {
    float eps = ws[W_EPS+(size_t)g*32];
    for (int s=0;s<16;s++){
      const float* inH = ws + W_H + (size_t)(s>0? s-1:0)*HBUF;
      for (int p = gwv; p < crows; p += GW){
        int gp = nb + p;
        float4 a0={0.f,0.f,0.f,0.f}, a1={0.f,0.f,0.f,0.f};
        #define HG(PP,CBB) { \
          const int* rp=ptr+PP; int e=rp[p+1]; \
          for(int k=rp[p]+sg;k<e;k+=4){ \
            float v=val[CBB+k]; int q=cidx[CBB+k]; \
            const float* sr = (s==0)? zc+(size_t)q*128 : inH+(size_t)(nb+q)*128; \
            float4 x0 = ((const float4*)sr)[chn*2]; \
            float4 x1 = ((const float4*)sr)[chn*2+1]; \
            a0.x+=v*x0.x; a0.y+=v*x0.y; a0.z+=v*x0.z; a0.w+=v*x0.w; \
            a1.x+=v*x1.x; a1.y+=v*x1.y; a1.z+=v*x1.z; a1.w+=v*x1.w; \
          } }
        if (g==0){ HG(P_L0, CB_L0) }
        else if (g==1){ HG(P_L1D, CB_L1D) HG(P_L1U, CB_L1U) }
        else { HG(P_L2, CB_L2) }
        #undef HG
        red4x2(a0, a1);
        if (sg==0){
          const float* ownr = (s==0)? zc+(size_t)p*128 : inH+(size_t)gp*128;
          float4 o0 = ((const float4*)ownr)[chn*2];
          float4 o1 = ((const float4*)ownr)[chn*2+1];
          float* dst;
          if (s<15) dst = ws + W_H + (size_t)s*HBUF + (size_t)gp*128;
          else {
            float* outp; size_t ostride;
            if(g==0){ outp=ws+W_SCAT+S0_OFF+256; ostride=384; }
            else if(g==1){ outp=ws+W_SCAT+S1_OFF+512; ostride=640; }
            else { outp=ws+W_SCAT+S2_OFF+256; ostride=384; }
            dst = outp + (size_t)p*ostride;
          }
          stc2(dst+chn*8,   make_float2(o0.x-eps*a0.x, o0.y-eps*a0.y));
          stc2(dst+chn*8+2, make_float2(o0.z-eps*a0.z, o0.w-eps*a0.w));
          stc2(dst+chn*8+4, make_float2(o1.x-eps*a1.x, o1.y-eps*a1.y));
          stc2(dst+chn*8+6, make_float2(o1.z-eps*a1.z, o1.w-eps*a1.w));
        }
      }
      if (s<15){ barx(ws, b, g, bbase, Ng, chk, lb, ph); ph++; }
    }
  }

  barx(ws, b, 3, 0, 2048, b==0, b, ph); ph++;   // global join: SCAT complete

  // ---- Phase E: projection GEMMs (blocks 0..191), K-tile 16 ----
  if (b < 192){
    const float* S; const float* W; float* outp; int K; int blk;
    if (b<32){       S=ws+W_SCAT+S0_OFF; W=ws+W_WCAT+WC0; outp=out;        K=384; blk=b; }
    else if (b<128){ S=ws+W_SCAT+S1_OFF; W=ws+W_WCAT+WC1; outp=out+131072; K=640; blk=b-32; }
    else {           S=ws+W_SCAT+S2_OFF; W=ws+W_WCAT+WC2; outp=out+524288; K=384; blk=b-128; }
    int r0=blk*32;
    int ty=t>>5, tx=t&31;
    float acc[4][4]={};
    for (int k0=0; k0<K; k0+=16){
      {
        int r=t>>3, kq=(t&7)*2;
        const float* src=S+(size_t)(r0+r)*K + k0+kq;
        Sl[r*17+kq]=src[0]; Sl[r*17+kq+1]=src[1];
      }
      {
        int kk=t>>4, cq=(t&15)*8;
        const float* src=W+(size_t)(k0+kk)*128+cq;
        #pragma unroll
        for(int i=0;i<8;i++) Wl[kk*128+cq+i]=src[i];
      }
      __syncthreads();
      #pragma unroll
      for(int k=0;k<16;k++){
        float sv[4], wvv2[4];
        #pragma unroll
        for(int i=0;i<4;i++) sv[i]=Sl[(ty*4+i)*17+k];
        #pragma unroll
        for(int i=0;i<4;i++) wvv2[i]=Wl[k*128+tx+32*i];
        #pragma unroll
        for(int a2=0;a2<4;a2++)
          #pragma unroll
          for(int b2=0;b2<4;b2++) acc[a2][b2]+=sv[a2]*wvv2[b2];
      }
      __syncthreads();
    }
    #pragma unroll
    for(int a2=0;a2<4;a2++)
      #pragma unroll
      for(int b2=0;b2<4;b2++){
        int r=r0+ty*4+a2, col=tx+32*b2;
        outp[(size_t)r*128+col]=fmaxf(acc[a2][b2],0.f);
      }
  }
}

// ---------------- host ----------------
extern "C" void kernel_launch(void* const* d_in, const int* in_sizes, int n_in,
                              void* d_out, int out_size, void* d_ws, size_t ws_size,
                              hipStream_t stream){
  const float* z0 =(const float*)d_in[0];
  const float* z1 =(const float*)d_in[1];
  const float* z2 =(const float*)d_in[2];
  const float* L0 =(const float*)d_in[3];
  const float* L1d=(const float*)d_in[4];
  const float* L1u=(const float*)d_in[5];
  const float* L2 =(const float*)d_in[6];
  const float* B1 =(const float*)d_in[7];
  const float* B2 =(const float*)d_in[8];
  const float* Wd =(const float*)d_in[9];
  const float* Wu =(const float*)d_in[10];
  const float* Wh =(const float*)d_in[11];
  const float* Wb1=(const float*)d_in[12];
  const float* Wb2=(const float*)d_in[13];
  const float* adw=(const float*)d_in[14];
  const float* adb=(const float*)d_in[15];
  const float* auw=(const float*)d_in[16];
  const float* aub=(const float*)d_in[17];
  float* ws=(float*)d_ws;
  int* wsi=(int*)d_ws;
  float* out=(float*)d_out;

  hipLaunchKernelGGL(k_wprep, dim3(64), dim3(256), 0, stream, Wd,Wu,Wh,Wb1,Wb2,ws);
  hipLaunchKernelGGL(k_count, dim3(3328), dim3(256), 0, stream, L0,L1d,L1u,L2,B1,B2, wsi+W_CNT);
  hipLaunchKernelGGL(k_prefix, dim3(8), dim3(256), 0, stream, wsi+W_CNT, wsi+W_PTR, wsi+W_CUR);
  hipLaunchKernelGGL(k_fill, dim3(3328), dim3(256), 0, stream, L0,L1d,L1u,L2,B1,B2, wsi+W_PTR, wsi+W_CIDX, ws+W_VAL);
  hipLaunchKernelGGL(k_fillT, dim3(1024), dim3(256), 0, stream, ws);
  hipLaunchKernelGGL(k_solve, dim3(2048), dim3(256), 0, stream,
                     ws, z0, z1, z2, adw, adb, auw, aub, out);
}

// Round 3
// 907.807 us; speedup vs baseline: 1.3874x; 1.2090x over previous
//
#include <hip/hip_runtime.h>
#include <string.h>

// ---------------- problem constants ----------------
constexpr int M_LZ = 64;   // Lanczos steps. 32 FAILED (err 384>350): Wigner spectrum,
                           // P^16 amplifies bottom edge ~2^16 -> need lambda_max to ~0.3%.

// CSR capacity per matrix (expected nnz * ~1.25)
constexpr int CAP_L0 = 26240, CAP_L1 = 118016, CAP_L2 = 52480, CAP_B1 = 39360, CAP_B2 = 78720;
constexpr int CB_L0 = 0;
constexpr int CB_L1D = CB_L0 + CAP_L0;
constexpr int CB_L1U = CB_L1D + CAP_L1;
constexpr int CB_L2  = CB_L1U + CAP_L1;
constexpr int CB_B1  = CB_L2 + CAP_L2;
constexpr int CB_B2  = CB_B1 + CAP_B1;
constexpr int CAP_TOT= CB_B2 + CAP_B2;   // 432832
constexpr int CB_B1T = CAP_TOT;
constexpr int CB_B2T = CB_B1T + CAP_B1;
constexpr int CAP_TOT2 = CB_B2T + CAP_B2; // 550912

// rowptr offsets (ints) within W_PTR region
constexpr int P_L0=0, P_L1D=1025, P_L1U=4098, P_L2=7171, P_B1=9220, P_B2=10245;
constexpr int P_B1T=13320, P_B2T=16393;   // region size 18444
// row-count offsets within W_CNT region
constexpr int C_L0=0, C_L1D=1024, C_L1U=4096, C_L2=7168, C_B1=9216, C_B2=10240;
constexpr int C_B1T=13312, C_B2T=16384;   // region size 18432

constexpr size_t HBUF  = (size_t)6144*128;          // 786432 words

// workspace layout (units: 4-byte words) -- unchanged total size
constexpr size_t W_CNT = 0;                         // 18432 ints (dead after prefix; first 16
                                                    //  128B lines reused as Krylov barrier leaves)
constexpr size_t W_PTR = 18432;
constexpr size_t W_CUR = W_PTR + 18444;
constexpr size_t W_CIDX= W_CUR + 5120;
constexpr size_t W_VAL = W_CIDX + CAP_TOT2;
constexpr size_t W_V0  = W_VAL + CAP_TOT2;          // 6144
constexpr size_t W_PK  = W_V0 + 6144;               // 64*6144*4
constexpr size_t W_TT  = W_PK + (size_t)64*6144*4;  // 3*64*32
constexpr size_t W_EPS = W_TT + 6144;
constexpr size_t W_UV  = W_EPS + 128;
// Krylov y_k buffers: y_1..y_15 (y_16 goes straight to SCAT harmonic column)
constexpr size_t W_H   = W_UV + 4*3072;             // 15*HBUF
constexpr size_t W_SCAT= W_H + 15*HBUF;
constexpr size_t S0_OFF= 0;                          // 1024 x 384
constexpr size_t S1_OFF= (size_t)1024*384;           // 3072 x 640
constexpr size_t S2_OFF= S1_OFF + (size_t)3072*640;  // 2048 x 384
constexpr size_t SCAT_TOT = S2_OFF + (size_t)2048*384;
constexpr size_t W_WCAT= W_SCAT + SCAT_TOT;
constexpr size_t WC0=0, WC1=(size_t)384*128, WC2=WC1+(size_t)640*128;
// per-block Lanczos slot lines [j][b] -> 8 words; [0]=seq [2..3]=(A,G) [4]=N
constexpr size_t W_SLOT= W_WCAT + (size_t)1408*128;  // 64*2048*8
constexpr size_t W_FLG = W_SLOT + 1048576;           // 2048*32
// release leaves: grp0..2 = Lanczos groups (lines 0..47), grp3 = global (lines 48..63)
constexpr size_t W_REL = W_FLG + 65536;              // 2048

__device__ __forceinline__ float wredf(float v){
  #pragma unroll
  for(int o=32;o;o>>=1) v += __shfl_xor(v,o,64);
  return v;
}
__device__ __forceinline__ int wredi(int v){
  #pragma unroll
  for(int o=32;o;o>>=1) v += __shfl_xor(v,o,64);
  return v;
}

// agent-scope (coherence-point) ops
__device__ __forceinline__ float ldc(const float* p){
  return __hip_atomic_load(p, __ATOMIC_RELAXED, __HIP_MEMORY_SCOPE_AGENT);
}
__device__ __forceinline__ float2 ldc2(const float* p){
  unsigned long long u = __hip_atomic_load((const unsigned long long*)p,
                          __ATOMIC_RELAXED, __HIP_MEMORY_SCOPE_AGENT);
  float2 r; memcpy(&r,&u,8); return r;
}
__device__ __forceinline__ void stc(float* p, float v){
  __hip_atomic_store(p, v, __ATOMIC_RELAXED, __HIP_MEMORY_SCOPE_AGENT);
}
__device__ __forceinline__ void stc2(float* p, float2 v){
  unsigned long long u; memcpy(&u,&v,8);
  __hip_atomic_store((unsigned long long*)p, u, __ATOMIC_RELAXED, __HIP_MEMORY_SCOPE_AGENT);
}
__device__ __forceinline__ int ldci(const int* p){
  return __hip_atomic_load(p, __ATOMIC_RELAXED, __HIP_MEMORY_SCOPE_AGENT);
}
__device__ __forceinline__ void stci(int* p, int v){
  __hip_atomic_store(p, v, __ATOMIC_RELAXED, __HIP_MEMORY_SCOPE_AGENT);
}

// ---- generic flag-array barrier, leaves at caller-provided base (16 x 128B lines) ----
__device__ __forceinline__ void barg(float* ws, int* leafs, int b, int lbase, int Ng,
                                     bool chk, int lidx, int ph){
  const int t = threadIdx.x;
  int* flg = (int*)ws + W_FLG;
  __builtin_amdgcn_s_waitcnt(0);   // drain this thread's stores
  __syncthreads();
  if (t==0) stci(flg + (size_t)b*32, ph+1);
  if (chk){
    for (int s=t; s<Ng; s+=256){
      const int* f = flg + (size_t)(lbase+s)*32;
      while (ldci(f) < ph+1) __builtin_amdgcn_s_sleep(1);
    }
    __syncthreads();
    if (t==0){
      #pragma unroll
      for (int i=0;i<16;i++) stci(leafs + (size_t)i*32, ph+1);
    }
    __syncthreads();
  } else {
    if (t==0){
      const int* rl = leafs + (size_t)(lidx&15)*32;
      while (ldci(rl) < ph+1) __builtin_amdgcn_s_sleep(1);
    }
    __syncthreads();
  }
}

// ---- Lanczos barrier: seq-embedded slot lines + (a,g,ib) payload in release leaves ----
__device__ __forceinline__ void bar_lz(float* ws, int b, int grp, int lbase, int Lg,
                                       bool chk, int lb, int ph, int j,
                                       float* shr, float* redm,
                                       float& a_o, float& g_o, float& ib_o){
  const int t = threadIdx.x, lane = t&63, wvv = t>>6;
  __builtin_amdgcn_s_waitcnt(0);   // drain PK / own stores
  __syncthreads();
  if (t==0){
    float A0=redm[0]+redm[1]+redm[2]+redm[3];
    float G0=redm[4]+redm[5]+redm[6]+redm[7];
    float N0=redm[8]+redm[9]+redm[10]+redm[11];
    float* sl = ws + W_SLOT + ((size_t)j*2048 + b)*8;
    stc2(sl+2, make_float2(A0,G0)); stc(sl+4, N0);
    __builtin_amdgcn_s_waitcnt(0);           // payload before seq
    stci((int*)sl, ph+1);
  }
  if (chk){
    float pa=0.f, pg=0.f, pn=0.f;
    for (int s=t; s<Lg; s+=256){
      const float* sl = ws + W_SLOT + ((size_t)j*2048 + lbase+s)*8;
      while (ldci((const int*)sl) < ph+1) __builtin_amdgcn_s_sleep(1);
      float2 ag = ldc2(sl+2); float nn = ldc(sl+4);
      pa+=ag.x; pg+=ag.y; pn+=nn;
    }
    pa=wredf(pa); pg=wredf(pg); pn=wredf(pn);
    if (lane==0){ shr[0*4+wvv]=pa; shr[1*4+wvv]=pg; shr[2*4+wvv]=pn; }
    __syncthreads();
    if (t==0){
      float a=shr[0]+shr[1]+shr[2]+shr[3];
      float g=shr[4]+shr[5]+shr[6]+shr[7];
      float n=shr[8]+shr[9]+shr[10]+shr[11];
      float ib = 1.f/sqrtf(fmaxf(n - a*a - g*g, 1e-20f));
      float* TT = ws + W_TT + (size_t)(grp*64 + j)*32;
      stc2(TT, make_float2(a,g)); stc(TT+2, n);
      #pragma unroll
      for (int i=0;i<16;i++){
        float* lf = ws + W_REL + (size_t)(grp*16+i)*32;
        stc2(lf+2, make_float2(a,g)); stc(lf+4, ib);
      }
      __builtin_amdgcn_s_waitcnt(0);   // payload globally visible before seq
      #pragma unroll
      for (int i=0;i<16;i++)
        stci((int*)(ws + W_REL) + (size_t)(grp*16+i)*32, ph+1);
      shr[0]=a; shr[1]=g; shr[2]=ib;
    }
    __syncthreads();
  } else {
    if (t==0){
      const float* lf = ws + W_REL + (size_t)(grp*16 + (lb&15))*32;
      while (ldci((const int*)lf) < ph+1) __builtin_amdgcn_s_sleep(1);
      float2 ag = ldc2(lf+2); float ib = ldc(lf+4);
      shr[0]=ag.x; shr[1]=ag.y; shr[2]=ib;
    }
    __syncthreads();
  }
  a_o = shr[0]; g_o = shr[1]; ib_o = shr[2];
}

// ---------------- weight prep + zeroing of counters/flags/slot-seqs ----------------
__global__ void k_wprep(const float* Wd,const float* Wu,const float* Wh,
                        const float* Wb1,const float* Wb2, float* ws){
  int t = blockIdx.x*256 + threadIdx.x;
  if (t >= 16384) return;
  int* wsi = (int*)ws;
  if (t < 5120) wsi[W_CNT + 13312 + t] = 0;          // transpose col counters
  if (t < 5120) wsi[W_CUR + t] = 0;                  // cursors
  for (int i=t; i<65536+2048; i+=16384) wsi[W_FLG+i] = 0;  // flags + releases
  for (int i=t; i<131072; i+=16384) wsi[W_SLOT + (size_t)i*8] = 0;  // slot seq words
  float sd = Wd[t]  + Wd[16384+t]  + Wd[32768+t];
  float su = Wu[t]  + Wu[16384+t]  + Wu[32768+t];
  float s1 = Wb1[t] + Wb1[16384+t] + Wb1[32768+t];
  float s2 = Wb2[t] + Wb2[16384+t] + Wb2[32768+t];
  float wh = Wh[t];
  float* W0 = ws + W_WCAT + WC0;
  float* W1 = ws + W_WCAT + WC1;
  float* W2 = ws + W_WCAT + WC2;
  W0[t]=sd; W0[16384+t]=s1; W0[32768+t]=wh;
  W1[t]=sd; W1[16384+t]=su; W1[32768+t]=s1; W1[49152+t]=s2; W1[65536+t]=wh;
  W2[t]=su; W2[16384+t]=s2; W2[32768+t]=wh;
}

// ---------------- CSR extraction (proven) ----------------
__device__ __forceinline__ void mat_meta(int wid, const float* L0,const float* L1d,const float* L1u,
    const float* L2,const float* B1,const float* B2,
    const float*& M,int& ncol,int& lrow,int& co,int& po,int& cb,int& cap,int& tco){
  if (wid < 1024){ M=L0;  ncol=1024; lrow=wid;        co=C_L0;  po=P_L0;  cb=CB_L0;  cap=CAP_L0; tco=-1; }
  else if (wid < 4096){ M=L1d; ncol=3072; lrow=wid-1024;  co=C_L1D; po=P_L1D; cb=CB_L1D; cap=CAP_L1; tco=-1; }
  else if (wid < 7168){ M=L1u; ncol=3072; lrow=wid-4096;  co=C_L1U; po=P_L1U; cb=CB_L1U; cap=CAP_L1; tco=-1; }
  else if (wid < 9216){ M=L2;  ncol=2048; lrow=wid-7168;  co=C_L2;  po=P_L2;  cb=CB_L2;  cap=CAP_L2; tco=-1; }
  else if (wid < 10240){ M=B1; ncol=3072; lrow=wid-9216;  co=C_B1;  po=P_B1;  cb=CB_B1;  cap=CAP_B1; tco=C_B1T; }
  else { M=B2; ncol=2048; lrow=wid-10240; co=C_B2;  po=P_B2;  cb=CB_B2;  cap=CAP_B2; tco=C_B2T; }
}

__global__ void k_count(const float* L0,const float* L1d,const float* L1u,const float* L2,
                        const float* B1,const float* B2,int* cnt){
  int wid = blockIdx.x*4 + (threadIdx.x>>6);
  int lane = threadIdx.x & 63;
  if (wid >= 13312) return;
  const float* M; int ncol,lrow,co,po,cb,cap,tco;
  mat_meta(wid,L0,L1d,L1u,L2,B1,B2,M,ncol,lrow,co,po,cb,cap,tco);
  const float4* row4 = (const float4*)(M + (size_t)lrow*ncol);
  int c = 0;
  for (int j0=0; j0<ncol; j0+=256){
    float4 v = row4[(j0>>2)+lane];
    int n0=v.x!=0.f, n1=v.y!=0.f, n2=v.z!=0.f, n3=v.w!=0.f;
    c += n0+n1+n2+n3;
    if (tco>=0){
      int jb = j0 + lane*4;
      if (n0) atomicAdd(cnt+tco+jb,   1);
      if (n1) atomicAdd(cnt+tco+jb+1, 1);
      if (n2) atomicAdd(cnt+tco+jb+2, 1);
      if (n3) atomicAdd(cnt+tco+jb+3, 1);
    }
  }
  c = wredi(c);
  if (lane==0) cnt[co+lrow] = c;
}

__global__ void k_prefix(const int* cnt, int* ptr, int* cur){
  __shared__ int lds[257];
  const int rows[8]={1024,3072,3072,2048,1024,3072,3072,2048};
  const int cofs[8]={C_L0,C_L1D,C_L1U,C_L2,C_B1,C_B2,C_B1T,C_B2T};
  const int pofs[8]={P_L0,P_L1D,P_L1U,P_L2,P_B1,P_B2,P_B1T,P_B2T};
  int b=blockIdx.x, t=threadIdx.x;
  int R=rows[b]; const int* c=cnt+cofs[b]; int* p=ptr+pofs[b];
  int* cc = (b==6)? cur : (b==7)? cur+3072 : nullptr;
  int chunk=(R+255)/256;
  int lo=t*chunk, hi=min(R,lo+chunk);
  int s=0;
  for(int i=lo;i<hi;i++) s+=c[i];
  lds[t]=s; __syncthreads();
  if(t==0){ int run=0; for(int i=0;i<256;i++){int x=lds[i];lds[i]=run;run+=x;} lds[256]=run; }
  __syncthreads();
  int run=lds[t];
  for(int i=lo;i<hi;i++){ p[i]=run; if(cc) cc[i]=run; run+=c[i]; }
  if(t==0) p[R]=lds[256];
}

__global__ void k_fill(const float* L0,const float* L1d,const float* L1u,const float* L2,
                       const float* B1,const float* B2,const int* ptr,int* cidx,float* val){
  int wid = blockIdx.x*4 + (threadIdx.x>>6);
  int lane = threadIdx.x & 63;
  if (wid >= 13312) return;
  const float* M; int ncol,lrow,co,po,cb,cap,tco;
  mat_meta(wid,L0,L1d,L1u,L2,B1,B2,M,ncol,lrow,co,po,cb,cap,tco);
  const float4* row4 = (const float4*)(M + (size_t)lrow*ncol);
  int base = ptr[po+lrow];
  int run = 0;
  for (int j0=0; j0<ncol; j0+=256){
    float4 v = row4[(j0>>2)+lane];
    int n0=v.x!=0.f, n1=v.y!=0.f, n2=v.z!=0.f, n3=v.w!=0.f;
    int local = n0+n1+n2+n3;
    int incl = local;
    #pragma unroll
    for (int o=1;o<64;o<<=1){
      int tmp = __shfl_up(incl,o,64);
      if (lane>=o) incl += tmp;
    }
    int tot = __shfl(incl,63,64);
    int pos = base + run + incl - local;
    int jb = j0 + lane*4;
    if (n0){ if(pos<cap){cidx[cb+pos]=jb;   val[cb+pos]=v.x;} pos++; }
    if (n1){ if(pos<cap){cidx[cb+pos]=jb+1; val[cb+pos]=v.y;} pos++; }
    if (n2){ if(pos<cap){cidx[cb+pos]=jb+2; val[cb+pos]=v.z;} pos++; }
    if (n3){ if(pos<cap){cidx[cb+pos]=jb+3; val[cb+pos]=v.w;} pos++; }
    run += tot;
  }
}

__global__ void k_fillT(float* ws){
  int wid = blockIdx.x*4 + (threadIdx.x>>6);
  int lane = threadIdx.x & 63;
  if (wid >= 4096) return;
  int* wsi=(int*)ws;
  const int* ptr=wsi+W_PTR; int* cidx=wsi+W_CIDX; float* val=ws+W_VAL;
  int* cur=wsi+W_CUR;
  if (wid < 1024){
    int r=wid;
    int e=ptr[P_B1+r+1];
    for(int k=ptr[P_B1+r]+lane;k<e;k+=64){
      int c=cidx[CB_B1+k]; float v=val[CB_B1+k];
      int pos=atomicAdd(cur+c,1);
      cidx[CB_B1T+pos]=r; val[CB_B1T+pos]=v;
    }
  } else {
    int r=wid-1024;
    int e=ptr[P_B2+r+1];
    for(int k=ptr[P_B2+r]+lane;k<e;k+=64){
      int c=cidx[CB_B2+k]; float v=val[CB_B2+k];
      int pos=atomicAdd(cur+3072+c,1);
      cidx[CB_B2T+pos]=r; val[CB_B2T+pos]=v;
    }
  }
}

// ================= FUSED PERSISTENT SOLVER =================
// 2048 blocks x 256 threads, 8 blocks/CU.
// Roles: blocks [0,768) = Lanczos, 2 rows/wave (32 lanes/row):
//   g0 [0,128)/1024 rows, g1 [128,512)/3072, g2 [512,768)/2048.
// Blocks [768,2048) = Krylov harmonic chain (y_k = (L/lam0)^k z, k=1..16,
//   plain barriers -- eps-independent!) + forward SpMMs, all OVERLAPPED with
//   the latency-bound Lanczos chain.
// After a global join: eig gives eps; a local combination pass applies
//   P^16 z = sum_k binom(16,k) (-eps*lam0)^k y_k. Then Phase E GEMMs.
// Flag schedule per block (monotonic): 1(A) [Krylov: 2..16] 31(post) 32(final).
__global__ __launch_bounds__(256,8) void k_solve(float* ws,
    const float* z0,const float* z1,const float* z2,
    const float* adw,const float* adb,const float* auw,const float* aub,
    float* out){
  const int b = blockIdx.x, t = threadIdx.x;
  const int wv = t>>6, lane = t&63;
  const int sg = lane>>4, chn = lane&15;
  const int* wsi=(const int*)ws;
  const int* ptr=wsi+W_PTR; const int* cidx=wsi+W_CIDX; const float* val=ws+W_VAL;

  __shared__ float smem[2616];             // 10464 B
  float* Sl  = smem;                       // [544]   phase E
  float* Wl  = smem + 544;                 // [2048]  phase E
  float* TTa = smem;                       // [64]    eig (alias, disjoint in time)
  float* TTb = smem + 64;                  // [64]
  float* redm= smem + 2592;                // [12]
  float* shr = smem + 2604;                // [12]

  int* grel = (int*)ws + W_REL + 48*32;    // global-barrier leaves (lines 48..63)

  // ---- Phase A: v_0 init + attention U,V + Krylov-leaf zeroing ----
  { int i = b*256+t;
    if (i < 6144){
      float invs = (i<1024)?0.03125f:(i<4096)?0.0180421959f:0.0220970869f;
      unsigned uu=(unsigned)i*2654435761u; uu^=uu>>16; uu*=2246822519u; uu^=uu>>13;
      stc(ws+W_V0+i, (uu&1)?invs:-invs);     // v_0
    }
  }
  { int gw = b*4+wv;
    if (gw < 3072){
      float2 x  = ((const float2*)(z1+(size_t)gw*128))[lane];
      float2 a0 = ((const float2*)adw)[lane];
      float2 a1 = ((const float2*)adw)[64+lane];
      float2 b0 = ((const float2*)auw)[lane];
      float2 b1 = ((const float2*)auw)[64+lane];
      float ud=x.x*a0.x+x.y*a0.y, vd=x.x*a1.x+x.y*a1.y;
      float uu=x.x*b0.x+x.y*b0.y, vu=x.x*b1.x+x.y*b1.y;
      ud=wredf(ud); vd=wredf(vd); uu=wredf(uu); vu=wredf(vu);
      if(lane==0){ stc(ws+W_UV+gw,ud); stc(ws+W_UV+3072+gw,vd);
                   stc(ws+W_UV+6144+gw,uu); stc(ws+W_UV+9216+gw,vu); }
    }
  }
  if (b==0 && t<16) stci((int*)ws + W_CNT + (size_t)t*32, 0);  // Krylov leaves
  barg(ws, grel, b, 0, 2048, b==0, b, 0);   // global: v_0, UV, leaves visible

  if (b < 768){
    // ==== Lanczos: 2 rows per wave (lanes 0-31 -> row p(hw=0), 32-63 -> p+1) ====
    int g, gbase, nb;
    if (b<128){ g=0; gbase=0;   nb=0;    }
    else if (b<512){ g=1; gbase=128; nb=1024; }
    else { g=2; gbase=512; nb=4096; }
    const int lb = b - gbase;
    const int Lg = (g==0)?128:(g==1)?384:256;
    const bool chk = (lb==0);
    const int hw = lane>>5, hl = lane&31;
    const int p  = lb*8 + wv*2 + hw;
    const int gp = nb + p;
    float a=0.f, gmm=0.f, ib=1.f;
    float vp_m1=0.f, vp_m2=0.f, wp_m1=0.f;   // own-row history (lanes 0/32)
    for (int j=0;j<M_LZ;j++){
      float wp=0.f;
      if (j==0){
        const float* v0 = ws + W_V0;
        #define GZ(PP,CBB) { const int* rp=ptr+PP; int e=rp[p+1]; \
          for (int k=rp[p]+hl;k<e;k+=32){ wp += val[CBB+k]*v0[nb+cidx[CBB+k]]; } }
        if (g==0){ GZ(P_L0,CB_L0) }
        else if (g==1){ GZ(P_L1D,CB_L1D) GZ(P_L1U,CB_L1U) }
        else { GZ(P_L2,CB_L2) }
        #undef GZ
      } else {
        const float4* pk = (const float4*)(ws + W_PK) + (size_t)(j-1)*6144 + nb;
        #define GP(PP,CBB) { const int* rp=ptr+PP; int e=rp[p+1]; \
          for (int k=rp[p]+hl;k<e;k+=32){ float v=val[CBB+k]; float4 pq=pk[cidx[CBB+k]]; \
            wp += v*((pq.x - a*pq.y - gmm*pq.z)*ib); } }
        if (g==0){ GP(P_L0,CB_L0) }
        else if (g==1){ GP(P_L1D,CB_L1D) GP(P_L1U,CB_L1U) }
        else { GP(P_L2,CB_L2) }
        #undef GP
      }
      #pragma unroll
      for (int o=16;o;o>>=1) wp += __shfl_xor(wp,o,64);   // half-wave reduce
      float rA=0.f, rG=0.f, rN=0.f;
      if (hl==0){
        float vp;
        if (j==0) vp = ws[W_V0+gp];
        else      vp = (wp_m1 - a*vp_m1 - gmm*vp_m2)*ib;
        float* pkw = ws + W_PK + ((size_t)j*6144 + gp)*4;
        stc2(pkw, make_float2(wp, vp)); stc(pkw+2, vp_m1);
        rA = vp*wp; rG = vp_m1*wp; rN = wp*wp;
        vp_m2 = vp_m1; vp_m1 = vp; wp_m1 = wp;
      }
      rA += __shfl_xor(rA,32,64); rG += __shfl_xor(rG,32,64); rN += __shfl_xor(rN,32,64);
      if (lane==0){ redm[0*4+wv]=rA; redm[1*4+wv]=rG; redm[2*4+wv]=rN; }
      bar_lz(ws, b, g, gbase, Lg, chk, lb, 1+j, j, shr, redm, a, gmm, ib);
    }
    // ---- eig (checker blocks only, first wave) ----
    if (chk && t<64){
      int i = t;
      double lo=1e300, hi=-1e300;
      if (i<M_LZ){
        const float* TT = ws + W_TT + (size_t)(g*64 + i)*32;
        float aa=TT[0], gg=TT[1], nn=TT[2];
        TTa[i]=aa; TTb[i]=sqrtf(fmaxf(nn-aa*aa-gg*gg,1e-20f));
      }
      if (i<M_LZ){
        double r=(i? fabs((double)TTb[i-1]):0.0) + (i<M_LZ-1? fabs((double)TTb[i]):0.0);
        lo=(double)TTa[i]-r; hi=(double)TTa[i]+r;
      }
      #pragma unroll
      for(int o=32;o;o>>=1){ lo=fmin(lo,__shfl_xor(lo,o,64)); hi=fmax(hi,__shfl_xor(hi,o,64)); }
      lo -= 1.0; hi += 1.0;
      for (int round=0; round<4; round++){
        double x = lo + (hi-lo)*(double)(i+1)/65.0;
        double d = 1.0; int cnt2=0;
        for (int k2=0;k2<M_LZ;k2++){
          double bi = k2? (double)TTb[k2-1] : 0.0;
          d = ((double)TTa[k2]-x) - bi*bi/d;
          if (d==0.0) d = -1e-300;
          if (d<0.0) cnt2++;
        }
        double nlo = (cnt2< M_LZ)? x : -1e300;
        double nhi = (cnt2==M_LZ)? x :  1e300;
        #pragma unroll
        for(int o=32;o;o>>=1){ nlo=fmax(nlo,__shfl_xor(nlo,o,64)); nhi=fmin(nhi,__shfl_xor(nhi,o,64)); }
        if (nlo>-1e299) lo=nlo;
        if (nhi< 1e299) hi=nhi;
      }
      double lam = 0.5*(lo+hi);
      if (i==0) stc(ws+W_EPS+(size_t)g*32, (lam>0.0)? (float)(1.0/lam) : 0.1f);
    }
  } else {
    // ==== Krylov blocks: y_k chain (k=1..16, plain barriers), then forward SpMMs ====
    const int kb = b - 768;
    const int hw = lane>>5;
    const int sgh = (lane>>4)&1;             // 2 nnz-subgroups per half-wave
    const int r = kb*8 + wv*2 + hw;          // 0..10239 (half-wave row id)
    const bool act = (r < 6144);
    int cg=0, nb2=0, lr=0; const float* zz=z0; float eps0=0.0625f;
    if (act){
      if (r<1024){ cg=0; nb2=0;    lr=r;      zz=z0; eps0=0.0625f;     }
      else if (r<4096){ cg=1; nb2=1024; lr=r-1024; zz=z1; eps0=(1.f/28.f); }
      else { cg=2; nb2=4096; lr=r-4096; zz=z2; eps0=0.0625f; }
    }
    for (int k2=1; k2<=16; k2++){
      if (act){
        float4 a0={0.f,0.f,0.f,0.f}, a1={0.f,0.f,0.f,0.f};
        const float* ybase = ws + W_H + (size_t)(k2>=2? k2-2:0)*HBUF;
        #define KG(PP,CBB) { const int* rp=ptr+PP; int e=rp[lr+1]; \
          for (int kk=rp[lr]+sgh; kk<e; kk+=2){ \
            float v=val[CBB+kk]; int q=cidx[CBB+kk]; \
            const float* sr = (k2==1)? zz+(size_t)q*128 : ybase+(size_t)(nb2+q)*128; \
            float4 x0=((const float4*)sr)[chn*2], x1=((const float4*)sr)[chn*2+1]; \
            a0.x+=v*x0.x; a0.y+=v*x0.y; a0.z+=v*x0.z; a0.w+=v*x0.w; \
            a1.x+=v*x1.x; a1.y+=v*x1.y; a1.z+=v*x1.z; a1.w+=v*x1.w; \
          } }
        if (cg==0){ KG(P_L0,CB_L0) }
        else if (cg==1){ KG(P_L1D,CB_L1D) KG(P_L1U,CB_L1U) }
        else { KG(P_L2,CB_L2) }
        #undef KG
        a0.x+=__shfl_xor(a0.x,16,64); a0.y+=__shfl_xor(a0.y,16,64);
        a0.z+=__shfl_xor(a0.z,16,64); a0.w+=__shfl_xor(a0.w,16,64);
        a1.x+=__shfl_xor(a1.x,16,64); a1.y+=__shfl_xor(a1.y,16,64);
        a1.z+=__shfl_xor(a1.z,16,64); a1.w+=__shfl_xor(a1.w,16,64);
        if ((lane&16)==0){
          float* dst;
          if (k2<16) dst = ws + W_H + (size_t)(k2-1)*HBUF + (size_t)r*128;
          else {
            if (cg==0)      dst = ws+W_SCAT+S0_OFF+256 + (size_t)lr*384;
            else if (cg==1) dst = ws+W_SCAT+S1_OFF+512 + (size_t)lr*640;
            else            dst = ws+W_SCAT+S2_OFF+256 + (size_t)lr*384;
          }
          stc2(dst+chn*8,   make_float2(eps0*a0.x, eps0*a0.y));
          stc2(dst+chn*8+2, make_float2(eps0*a0.z, eps0*a0.w));
          stc2(dst+chn*8+4, make_float2(eps0*a1.x, eps0*a1.y));
          stc2(dst+chn*8+6, make_float2(eps0*a1.z, eps0*a1.w));
        }
      }
      if (k2<16) barg(ws, (int*)ws + W_CNT, b, 768, 1280, b==768, kb, k2);
    }
    // ---- forward SpMMs (4-way nnz-parallel) ----
    for (int wid2 = kb*4+wv; wid2 < 18432; wid2 += 5120){
      int task,p2;
      if(wid2<1024){task=0;p2=wid2;}
      else if(wid2<2048){task=1;p2=wid2-1024;}
      else if(wid2<5120){task=2;p2=wid2-2048;}
      else if(wid2<8192){task=3;p2=wid2-5120;}
      else if(wid2<11264){task=4;p2=wid2-8192;}
      else if(wid2<13312){task=5;p2=wid2-11264;}
      else if(wid2<16384){task=6;p2=wid2-13312;}
      else {task=7;p2=wid2-16384;}
      const float* in; const int* rp; int cb2; float* outp; int ostride;
      int mode=0; float Vp=0.f, bb=0.f; const float* U=nullptr;
      switch(task){
        case 0: rp=ptr+P_L0;  cb2=CB_L0;  in=z0; outp=ws+W_SCAT+S0_OFF+0;   ostride=384; break;
        case 1: rp=ptr+P_B1;  cb2=CB_B1;  in=z1; outp=ws+W_SCAT+S0_OFF+128; ostride=384; break;
        case 2: rp=ptr+P_L1D; cb2=CB_L1D; in=z1; outp=ws+W_SCAT+S1_OFF+0;   ostride=640;
                mode=1; U=ws+W_UV; Vp=ws[W_UV+3072+p2]; bb=adb[0]; break;
        case 3: rp=ptr+P_L1U; cb2=CB_L1U; in=z1; outp=ws+W_SCAT+S1_OFF+128; ostride=640;
                mode=1; U=ws+W_UV+6144; Vp=ws[W_UV+9216+p2]; bb=aub[0]; break;
        case 4: rp=ptr+P_B2;  cb2=CB_B2;  in=z2; outp=ws+W_SCAT+S1_OFF+384; ostride=640; break;
        case 5: rp=ptr+P_L2;  cb2=CB_L2;  in=z2; outp=ws+W_SCAT+S2_OFF+0;   ostride=384; break;
        case 6: rp=ptr+P_B1T; cb2=CB_B1T; in=z0; outp=ws+W_SCAT+S1_OFF+256; ostride=640; break;
        default:rp=ptr+P_B2T; cb2=CB_B2T; in=z1; outp=ws+W_SCAT+S2_OFF+128; ostride=384; break;
      }
      float4 a0={0.f,0.f,0.f,0.f}, a1={0.f,0.f,0.f,0.f};
      int e=rp[p2+1];
      for (int k=rp[p2]+sg; k<e; k+=4){
        int q = cidx[cb2+k];
        float v;
        if (mode) v = 1.0f/(1.0f+__expf(-(U[q]+Vp+bb)));
        else v = val[cb2+k];
        const float* sr = in + (size_t)q*128;
        float4 x0 = ((const float4*)sr)[chn*2];
        float4 x1 = ((const float4*)sr)[chn*2+1];
        a0.x+=v*x0.x; a0.y+=v*x0.y; a0.z+=v*x0.z; a0.w+=v*x0.w;
        a1.x+=v*x1.x; a1.y+=v*x1.y; a1.z+=v*x1.z; a1.w+=v*x1.w;
      }
      // fold 4 nnz-subgroups
      #pragma unroll
      for (int o=16;o<=32;o<<=1){
        a0.x+=__shfl_xor(a0.x,o,64); a0.y+=__shfl_xor(a0.y,o,64);
        a0.z+=__shfl_xor(a0.z,o,64); a0.w+=__shfl_xor(a0.w,o,64);
        a1.x+=__shfl_xor(a1.x,o,64); a1.y+=__shfl_xor(a1.y,o,64);
        a1.z+=__shfl_xor(a1.z,o,64); a1.w+=__shfl_xor(a1.w,o,64);
      }
      if (sg==0){
        float* dst = outp + (size_t)p2*ostride;
        stc2(dst+chn*8,   make_float2(a0.x,a0.y));
        stc2(dst+chn*8+2, make_float2(a0.z,a0.w));
        stc2(dst+chn*8+4, make_float2(a1.x,a1.y));
        stc2(dst+chn*8+6, make_float2(a1.z,a1.w));
      }
    }
  }

  // ---- global join: TT/eps + y_k + SCAT forward parts all visible ----
  barg(ws, grel, b, 0, 2048, b==1, b, 30);

  // ---- combination pass: h = sum_{k=0}^{16} binom(16,k) (-eps*lam0)^k y_k ----
  { int r = b*4+wv;
    if (r < 6144){
      int cg = (r<1024)?0:(r<4096)?1:2;
      int lr = r - ((cg==0)?0:(cg==1)?1024:4096);
      const float* zz = (cg==0)?z0:(cg==1)?z1:z2;
      float lam0 = (cg==1)?28.f:16.f;
      float eps  = ws[W_EPS+(size_t)cg*32];
      float rr = eps*lam0;
      float* hc;
      if (cg==0)      hc = ws+W_SCAT+S0_OFF+256 + (size_t)lr*384;
      else if (cg==1) hc = ws+W_SCAT+S1_OFF+512 + (size_t)lr*640;
      else            hc = ws+W_SCAT+S2_OFF+256 + (size_t)lr*384;
      const float BIN[17] = {1.f,16.f,120.f,560.f,1820.f,4368.f,8008.f,11440.f,12870.f,
                             11440.f,8008.f,4368.f,1820.f,560.f,120.f,16.f,1.f};
      float2 acc = ((const float2*)(zz + (size_t)lr*128))[lane];
      float rk = 1.f;
      #pragma unroll
      for (int k2=1;k2<=15;k2++){
        rk *= -rr;
        float2 y = ((const float2*)(ws + W_H + (size_t)(k2-1)*HBUF + (size_t)r*128))[lane];
        float c = BIN[k2]*rk;
        acc.x += c*y.x; acc.y += c*y.y;
      }
      rk *= -rr;                              // k=16, binom=1
      float2 y16 = ((const float2*)hc)[lane];
      acc.x += rk*y16.x; acc.y += rk*y16.y;
      stc2(hc + (size_t)lane*2, acc);
    }
  }
  barg(ws, grel, b, 0, 2048, b==1, b, 31);   // harmonic columns complete

  // ---- Phase E: projection GEMMs (blocks 0..191), K-tile 16 ----
  if (b < 192){
    const float* S; const float* W; float* outp; int K; int blk;
    if (b<32){       S=ws+W_SCAT+S0_OFF; W=ws+W_WCAT+WC0; outp=out;        K=384; blk=b; }
    else if (b<128){ S=ws+W_SCAT+S1_OFF; W=ws+W_WCAT+WC1; outp=out+131072; K=640; blk=b-32; }
    else {           S=ws+W_SCAT+S2_OFF; W=ws+W_WCAT+WC2; outp=out+524288; K=384; blk=b-128; }
    int r0=blk*32;
    int ty=t>>5, tx=t&31;
    float acc[4][4]={};
    for (int k0=0; k0<K; k0+=16){
      {
        int r=t>>3, kq=(t&7)*2;
        const float* src=S+(size_t)(r0+r)*K + k0+kq;
        Sl[r*17+kq]=src[0]; Sl[r*17+kq+1]=src[1];
      }
      {
        int kk=t>>4, cq=(t&15)*8;
        const float* src=W+(size_t)(k0+kk)*128+cq;
        #pragma unroll
        for(int i=0;i<8;i++) Wl[kk*128+cq+i]=src[i];
      }
      __syncthreads();
      #pragma unroll
      for(int k=0;k<16;k++){
        float sv[4], wvv2[4];
        #pragma unroll
        for(int i=0;i<4;i++) sv[i]=Sl[(ty*4+i)*17+k];
        #pragma unroll
        for(int i=0;i<4;i++) wvv2[i]=Wl[k*128+tx+32*i];
        #pragma unroll
        for(int a2=0;a2<4;a2++)
          #pragma unroll
          for(int b2=0;b2<4;b2++) acc[a2][b2]+=sv[a2]*wvv2[b2];
      }
      __syncthreads();
    }
    #pragma unroll
    for(int a2=0;a2<4;a2++)
      #pragma unroll
      for(int b2=0;b2<4;b2++){
        int r=r0+ty*4+a2, col=tx+32*b2;
        outp[(size_t)r*128+col]=fmaxf(acc[a2][b2],0.f);
      }
  }
}

// ---------------- host ----------------
extern "C" void kernel_launch(void* const* d_in, const int* in_sizes, int n_in,
                              void* d_out, int out_size, void* d_ws, size_t ws_size,
                              hipStream_t stream){
  const float* z0 =(const float*)d_in[0];
  const float* z1 =(const float*)d_in[1];
  const float* z2 =(const float*)d_in[2];
  const float* L0 =(const float*)d_in[3];
  const float* L1d=(const float*)d_in[4];
  const float* L1u=(const float*)d_in[5];
  const float* L2 =(const float*)d_in[6];
  const float* B1 =(const float*)d_in[7];
  const float* B2 =(const float*)d_in[8];
  const float* Wd =(const float*)d_in[9];
  const float* Wu =(const float*)d_in[10];
  const float* Wh =(const float*)d_in[11];
  const float* Wb1=(const float*)d_in[12];
  const float* Wb2=(const float*)d_in[13];
  const float* adw=(const float*)d_in[14];
  const float* adb=(const float*)d_in[15];
  const float* auw=(const float*)d_in[16];
  const float* aub=(const float*)d_in[17];
  float* ws=(float*)d_ws;
  int* wsi=(int*)d_ws;
  float* out=(float*)d_out;

  hipLaunchKernelGGL(k_wprep, dim3(64), dim3(256), 0, stream, Wd,Wu,Wh,Wb1,Wb2,ws);
  hipLaunchKernelGGL(k_count, dim3(3328), dim3(256), 0, stream, L0,L1d,L1u,L2,B1,B2, wsi+W_CNT);
  hipLaunchKernelGGL(k_prefix, dim3(8), dim3(256), 0, stream, wsi+W_CNT, wsi+W_PTR, wsi+W_CUR);
  hipLaunchKernelGGL(k_fill, dim3(3328), dim3(256), 0, stream, L0,L1d,L1u,L2,B1,B2, wsi+W_PTR, wsi+W_CIDX, ws+W_VAL);
  hipLaunchKernelGGL(k_fillT, dim3(1024), dim3(256), 0, stream, ws);
  hipLaunchKernelGGL(k_solve, dim3(2048), dim3(256), 0, stream,
                     ws, z0, z1, z2, adw, adb, auw, aub, out);
}